// Round 1
// baseline (418.339 us; speedup 1.0000x reference)
//
#include <hip/hip_runtime.h>
#include <cmath>

#define DDIM 128
#define NPTS 3136   // 56*56
#define BATCH 16
#define PROT 2000
#define TP 64
#define TN 64

// ---------------- p2[p] = sum_d proto[p][d]^2 ----------------
__global__ void p2_kernel(const float* __restrict__ proto, float* __restrict__ p2) {
    int p = blockIdx.x * blockDim.x + threadIdx.x;
    if (p >= PROT) return;
    const float4* pr = reinterpret_cast<const float4*>(proto + (size_t)p * DDIM);
    float s = 0.f;
    #pragma unroll
    for (int i = 0; i < DDIM / 4; ++i) {
        float4 v = pr[i];
        s += v.x * v.x + v.y * v.y + v.z * v.z + v.w * v.w;
    }
    p2[p] = s;
}

// ---------------- x2[b*NPTS+n] = sum_d x[b][d][n]^2 ----------------
__global__ void x2_kernel(const float* __restrict__ x, float* __restrict__ x2) {
    int idx = blockIdx.x * blockDim.x + threadIdx.x; // b*NPTS + n
    if (idx >= BATCH * NPTS) return;
    int b = idx / NPTS, n = idx - b * NPTS;
    const float* xp = x + (size_t)b * DDIM * NPTS + n;
    float s = 0.f;
    #pragma unroll 8
    for (int d = 0; d < DDIM; ++d) {
        float v = xp[(size_t)d * NPTS];
        s += v * v;
    }
    x2[idx] = s;
}

// ---------------- main kernel ----------------
// grid: (ceil(PROT/TP)=32, BATCH=16), block 256
__global__ __launch_bounds__(256, 2)
void proto_main(const float* __restrict__ x, const float* __restrict__ proto,
                const float* __restrict__ p2, const float* __restrict__ x2,
                float* __restrict__ out) {
    __shared__ __align__(16) float xs[DDIM][TN];   // 32 KB
    __shared__ __align__(16) float pst[DDIM][TP];  // 32 KB (transposed proto tile)
    __shared__ float p2s[TP];
    __shared__ float x2s[TN];
    __shared__ float red_d2[16][TP];               // 4 KB
    __shared__ int   red_n[16][TP];                // 4 KB
    __shared__ int   bestn_s[TP];

    const int b = blockIdx.y;
    const int pbase = blockIdx.x * TP;
    const int tid = threadIdx.x;

    // ---- stage prototype tile (transposed) + p2s, once per block ----
    {
        #pragma unroll
        for (int it = 0; it < (TP * DDIM / 4) / 256; ++it) {  // 8 iters
            int idx = it * 256 + tid;          // quad index
            int p = idx / (DDIM / 4);          // 0..63
            int dq = idx - p * (DDIM / 4);     // 0..31
            int gp = min(pbase + p, PROT - 1);
            float4 v = reinterpret_cast<const float4*>(proto)[(size_t)gp * (DDIM / 4) + dq];
            pst[dq * 4 + 0][p] = v.x;
            pst[dq * 4 + 1][p] = v.y;
            pst[dq * 4 + 2][p] = v.z;
            pst[dq * 4 + 3][p] = v.w;
        }
        if (tid < TP) p2s[tid] = p2[min(pbase + tid, PROT - 1)];
    }

    const int tn = tid >> 4;   // 0..15  (n-group)
    const int tp = tid & 15;   // 0..15  (p-group)

    float best[4];
    int bestn[4];
    #pragma unroll
    for (int j = 0; j < 4; ++j) { best[j] = 1e30f; bestn[j] = 0; }

    for (int n0 = 0; n0 < NPTS; n0 += TN) {
        __syncthreads();   // protect xs/x2s from previous iteration readers
        // ---- stage x tile: xs[d][n] for n in [n0, n0+64) ----
        {
            int r = tid >> 4;   // 0..15
            int c = tid & 15;   // 0..15
            #pragma unroll
            for (int it = 0; it < 8; ++it) {
                int row = it * 16 + r;
                float4 v = *reinterpret_cast<const float4*>(
                    x + ((size_t)(b * DDIM + row)) * NPTS + n0 + c * 4);
                *reinterpret_cast<float4*>(&xs[row][c * 4]) = v;
            }
        }
        if (tid < TN) x2s[tid] = x2[b * NPTS + n0 + tid];
        __syncthreads();

        // ---- 4x4 register-tile dot products over d ----
        float acc[4][4];
        #pragma unroll
        for (int i = 0; i < 4; ++i)
            #pragma unroll
            for (int j = 0; j < 4; ++j) acc[i][j] = 0.f;

        #pragma unroll 16
        for (int d = 0; d < DDIM; ++d) {
            const float4 a = *reinterpret_cast<const float4*>(&xs[d][tn * 4]);
            const float4 bv = *reinterpret_cast<const float4*>(&pst[d][tp * 4]);
            const float av[4] = {a.x, a.y, a.z, a.w};
            const float bw[4] = {bv.x, bv.y, bv.z, bv.w};
            #pragma unroll
            for (int i = 0; i < 4; ++i)
                #pragma unroll
                for (int j = 0; j < 4; ++j)
                    acc[i][j] = fmaf(av[i], bw[j], acc[i][j]);
        }

        // ---- fold into per-thread running min/argmin (ascending n => first-occurrence) ----
        #pragma unroll
        for (int i = 0; i < 4; ++i) {
            float xv = x2s[tn * 4 + i];
            int n = n0 + tn * 4 + i;
            #pragma unroll
            for (int j = 0; j < 4; ++j) {
                float d2 = xv + p2s[tp * 4 + j] - 2.0f * acc[i][j];
                if (d2 < best[j]) { best[j] = d2; bestn[j] = n; }
            }
        }
    }

    // ---- cross-thread reduction over the 16 n-groups ----
    #pragma unroll
    for (int j = 0; j < 4; ++j) {
        red_d2[tn][tp * 4 + j] = best[j];
        red_n[tn][tp * 4 + j] = bestn[j];
    }
    __syncthreads();

    if (tid < TP) {
        float bd = red_d2[0][tid];
        int bn = red_n[0][tid];
        #pragma unroll
        for (int t = 1; t < 16; ++t) {
            float dv = red_d2[t][tid];
            int nv = red_n[t][tid];
            if (dv < bd || (dv == bd && nv < bn)) { bd = dv; bn = nv; }
        }
        int gp = pbase + tid;
        if (gp < PROT) {
            float d2c = fmaxf(bd, 0.f);
            float dmin = sqrtf(d2c);
            float sim = logf((dmin + 1.0f) / (dmin + 1e-7f));
            out[(size_t)b * PROT + gp] = sim;                       // max_similarity
            out[(size_t)BATCH * PROT + (size_t)b * PROT + gp] = dmin; // min_distances
        }
        bestn_s[tid] = bn;
    }
    __syncthreads();

    // ---- gather min_features: 64 p x 128 d, 256 threads ----
    {
        int pl = tid >> 2;            // 0..63
        int dbase = (tid & 3) * 32;   // 0,32,64,96
        int gp = pbase + pl;
        if (gp < PROT) {
            int n = bestn_s[pl];
            float* dst = out + (size_t)2 * BATCH * PROT + ((size_t)(b * PROT + gp)) * DDIM + dbase;
            const float* src = x + ((size_t)(b * DDIM + dbase)) * NPTS + n;
            #pragma unroll 8
            for (int d = 0; d < 32; ++d) dst[d] = src[(size_t)d * NPTS];
        }
    }
}

extern "C" void kernel_launch(void* const* d_in, const int* in_sizes, int n_in,
                              void* d_out, int out_size, void* d_ws, size_t ws_size,
                              hipStream_t stream) {
    const float* x = (const float*)d_in[0];       // [16,128,56,56]
    const float* proto = (const float*)d_in[1];   // [1,2000,128]
    float* out = (float*)d_out;                   // 32000 + 32000 + 4096000 floats
    float* ws = (float*)d_ws;
    float* p2 = ws;                 // 2000 floats
    float* x2 = ws + 2048;          // 16*3136 = 50176 floats

    p2_kernel<<<(PROT + 255) / 256, 256, 0, stream>>>(proto, p2);
    x2_kernel<<<(BATCH * NPTS + 255) / 256, 256, 0, stream>>>(x, x2);

    dim3 grid((PROT + TP - 1) / TP, BATCH);  // (32, 16)
    proto_main<<<grid, 256, 0, stream>>>(x, proto, p2, x2, out);
}

// Round 2
// 219.085 us; speedup vs baseline: 1.9095x; 1.9095x over previous
//
#include <hip/hip_runtime.h>
#include <hip/hip_bf16.h>
#include <cmath>

#define DDIM 128
#define NPTS 3136   // 56*56
#define BATCH 16
#define PROT 2000
#define PPAD 2048   // 32 tiles * 64

typedef __attribute__((ext_vector_type(8))) short bf16x8;
typedef __attribute__((ext_vector_type(4))) float f32x4;
typedef __attribute__((ext_vector_type(4))) unsigned int u32x4;

// ---- workspace layout (float indices) ----
#define WS_X2   0                      // 50176 floats
#define WS_N1   50176                  // 32768 ints
#define WS_N2   82944                  // 32768 ints
#define WS_PT   115712                 // 262144 floats = 524288 shorts (2048x256)
#define WS_XT   377856                 // 6422528 floats = 12845056 shorts (16*3136*256)
#define WS_NEED ((size_t)(377856 + 6422528) * 4)

// ---------------- bf16 split helpers ----------------
__device__ inline unsigned short bf16rn(float a) {
    unsigned u = __float_as_uint(a);
    unsigned r = u + 0x7FFFu + ((u >> 16) & 1u);
    return (unsigned short)(r >> 16);
}
__device__ inline void split2(float a, unsigned short& h, unsigned short& l) {
    h = bf16rn(a);
    float hf = __uint_as_float(((unsigned)h) << 16);
    l = bf16rn(a - hf);
}

// ---------------- prototype pre-pass: split to [p][kk][hi/lo][32] ----------------
__global__ void pp_p(const float* __restrict__ proto, unsigned short* __restrict__ pt) {
    int p = blockIdx.x * blockDim.x + threadIdx.x; // 0..2047
    if (p >= PPAD) return;
    int ps = min(p, PROT - 1);
    const float* src = proto + (size_t)ps * DDIM;
    unsigned short* dst = pt + (size_t)p * 256;
    for (int kk = 0; kk < 4; ++kk) {
        for (int j = 0; j < 32; ++j) {
            unsigned short h, l;
            split2(src[kk * 32 + j], h, l);
            dst[kk * 64 + j] = h;
            dst[kk * 64 + 32 + j] = l;
        }
    }
}

// ---------------- x pre-pass: transpose+split to xt[b][n][kk][hi/lo][32], plus x2 ----------------
__global__ __launch_bounds__(256)
void pp_x(const float* __restrict__ x, unsigned short* __restrict__ xt,
          float* __restrict__ x2) {
    __shared__ float xs[DDIM][64];
    int b = blockIdx.y;
    int n0 = blockIdx.x * 64;
    int tid = threadIdx.x;
    {
        int r = tid >> 4, c = tid & 15;
        #pragma unroll
        for (int it = 0; it < 8; ++it) {
            int row = it * 16 + r;
            f32x4 v = *(const f32x4*)(x + ((size_t)(b * DDIM + row)) * NPTS + n0 + c * 4);
            *(f32x4*)(&xs[row][c * 4]) = v;
        }
    }
    __syncthreads();
    if (tid < 64) {
        float s = 0.f;
        #pragma unroll 8
        for (int d = 0; d < DDIM; ++d) { float v = xs[d][tid]; s = fmaf(v, v, s); }
        x2[b * NPTS + n0 + tid] = s;
    }
    int n = tid & 63, kk = tid >> 6;
    unsigned int hw[16], lw[16];
    #pragma unroll
    for (int j = 0; j < 16; ++j) {
        unsigned short h0, l0, h1, l1;
        split2(xs[kk * 32 + 2 * j][n], h0, l0);
        split2(xs[kk * 32 + 2 * j + 1][n], h1, l1);
        hw[j] = (unsigned)h0 | ((unsigned)h1 << 16);
        lw[j] = (unsigned)l0 | ((unsigned)l1 << 16);
    }
    unsigned short* dst = xt + ((size_t)(b * NPTS + n0 + n)) * 256 + kk * 64;
    #pragma unroll
    for (int q = 0; q < 4; ++q) {
        ((u32x4*)dst)[q]        = *(u32x4*)(&hw[q * 4]);
        ((u32x4*)(dst + 32))[q] = *(u32x4*)(&lw[q * 4]);
    }
}

// ---------------- main MFMA kernel ----------------
// grid (BATCH=16, 32 p-tiles), block 256 = 4 waves; waves split the n-chunks.
__global__ __launch_bounds__(256, 2)
void proto_mfma(const unsigned short* __restrict__ xt,
                const unsigned short* __restrict__ pt,
                const float* __restrict__ x2,
                int* __restrict__ n1w, int* __restrict__ n2w) {
    int b = blockIdx.x;
    int pbase = blockIdx.y * 64;
    int tid = threadIdx.x;
    int lane = tid & 63, wave = tid >> 6;
    int l15 = lane & 15, lg = lane >> 4;

    // B fragments: 4 psubs x 4 kchunks x {hi,lo} -> resident all kernel (128 VGPR)
    bf16x8 Bf[4][4][2];
    #pragma unroll
    for (int ps = 0; ps < 4; ++ps) {
        int p = pbase + ps * 16 + l15;
        const bf16x8* bp = (const bf16x8*)(pt + (size_t)p * 256 + lg * 8);
        #pragma unroll
        for (int kk = 0; kk < 4; ++kk) {
            #pragma unroll
            for (int s = 0; s < 2; ++s)
                Bf[ps][kk][s] = bp[kk * 8 + s * 4];
        }
    }

    const unsigned short* aBase = xt + ((size_t)b * NPTS + l15) * 256 + lg * 8;
    const float* x2b = x2 + b * NPTS + lg * 4;

    float b1[4], b2[4];
    int   i1[4], i2[4];
    #pragma unroll
    for (int ps = 0; ps < 4; ++ps) { b1[ps] = 3e38f; b2[ps] = 3e38f; i1[ps] = 0; i2[ps] = 0; }

    #pragma unroll 1
    for (int c = wave; c < NPTS / 16; c += 4) {
        const bf16x8* ap = (const bf16x8*)(aBase + (size_t)c * 4096);
        bf16x8 Ah[4], Al[4];
        #pragma unroll
        for (int kk = 0; kk < 4; ++kk) { Ah[kk] = ap[kk * 8]; Al[kk] = ap[kk * 8 + 4]; }
        float x2r[4];
        #pragma unroll
        for (int rr = 0; rr < 4; ++rr) x2r[rr] = x2b[c * 16 + rr];

        f32x4 acc[4];
        #pragma unroll
        for (int ps = 0; ps < 4; ++ps) acc[ps] = {0.f, 0.f, 0.f, 0.f};

        #pragma unroll
        for (int kk = 0; kk < 4; ++kk) {
            #pragma unroll
            for (int ps = 0; ps < 4; ++ps)
                acc[ps] = __builtin_amdgcn_mfma_f32_16x16x32_bf16(Ah[kk], Bf[ps][kk][0], acc[ps], 0, 0, 0);
            #pragma unroll
            for (int ps = 0; ps < 4; ++ps)
                acc[ps] = __builtin_amdgcn_mfma_f32_16x16x32_bf16(Ah[kk], Bf[ps][kk][1], acc[ps], 0, 0, 0);
            #pragma unroll
            for (int ps = 0; ps < 4; ++ps)
                acc[ps] = __builtin_amdgcn_mfma_f32_16x16x32_bf16(Al[kk], Bf[ps][kk][0], acc[ps], 0, 0, 0);
        }

        // key = x2[n] - 2*dot  (= d2 - p2[p]; p2 constant per slot, dropped)
        int nb = c * 16 + lg * 4;
        #pragma unroll
        for (int ps = 0; ps < 4; ++ps) {
            #pragma unroll
            for (int rr = 0; rr < 4; ++rr) {
                float v = fmaf(acc[ps][rr], -2.f, x2r[rr]);
                int n = nb + rr;
                bool c1 = v < b1[ps];
                bool c2 = v < b2[ps];
                i2[ps] = c1 ? i1[ps] : (c2 ? n : i2[ps]);
                b2[ps] = c1 ? b1[ps] : (c2 ? v : b2[ps]);
                i1[ps] = c1 ? n : i1[ps];
                b1[ps] = c1 ? v : b1[ps];
            }
        }
    }

    // ---- reduce across the 4 row-groups (lanes l, l+16, l+32, l+48) ----
    #pragma unroll
    for (int m = 16; m <= 32; m <<= 1) {
        #pragma unroll
        for (int ps = 0; ps < 4; ++ps) {
            float c1v = __shfl_xor(b1[ps], m, 64);
            float c2v = __shfl_xor(b2[ps], m, 64);
            int   cn1 = __shfl_xor(i1[ps], m, 64);
            int   cn2 = __shfl_xor(i2[ps], m, 64);
            bool cl = (c1v < b1[ps]) || (c1v == b1[ps] && cn1 < i1[ps]);
            float m1 = cl ? c1v : b1[ps]; int mn1 = cl ? cn1 : i1[ps];
            float w1 = cl ? b1[ps] : c1v; int wn1 = cl ? i1[ps] : cn1;
            bool t = (b2[ps] < c2v) || (b2[ps] == c2v && i2[ps] < cn2);
            float s2 = t ? b2[ps] : c2v; int sn2 = t ? i2[ps] : cn2;
            bool u = (w1 < s2) || (w1 == s2 && wn1 < sn2);
            b1[ps] = m1; i1[ps] = mn1;
            b2[ps] = u ? w1 : s2; i2[ps] = u ? wn1 : sn2;
        }
    }

    // ---- reduce across the 4 waves (n-split) via LDS ----
    __shared__ float rb1[4][64], rb2[4][64];
    __shared__ int   rn1[4][64], rn2[4][64];
    if (l15 == lane) { // lane < 16
        #pragma unroll
        for (int ps = 0; ps < 4; ++ps) {
            rb1[wave][ps * 16 + l15] = b1[ps];
            rb2[wave][ps * 16 + l15] = b2[ps];
            rn1[wave][ps * 16 + l15] = i1[ps];
            rn2[wave][ps * 16 + l15] = i2[ps];
        }
    }
    __syncthreads();
    if (tid < 64) {
        float B1 = rb1[0][tid], B2 = rb2[0][tid];
        int   N1 = rn1[0][tid], N2 = rn2[0][tid];
        #pragma unroll
        for (int w = 1; w < 4; ++w) {
            float c1v = rb1[w][tid], c2v = rb2[w][tid];
            int   cn1 = rn1[w][tid], cn2 = rn2[w][tid];
            bool cl = (c1v < B1) || (c1v == B1 && cn1 < N1);
            float m1 = cl ? c1v : B1; int mn1 = cl ? cn1 : N1;
            float w1 = cl ? B1 : c1v; int wn1 = cl ? N1 : cn1;
            bool t = (B2 < c2v) || (B2 == c2v && N2 < cn2);
            float s2 = t ? B2 : c2v; int sn2 = t ? N2 : cn2;
            bool u = (w1 < s2) || (w1 == s2 && wn1 < sn2);
            B1 = m1; N1 = mn1;
            B2 = u ? w1 : s2; N2 = u ? wn1 : sn2;
        }
        n1w[(size_t)b * PPAD + pbase + tid] = N1;
        n2w[(size_t)b * PPAD + pbase + tid] = N2;
    }
}

// ---------------- exact fp32 fixup + all output writes ----------------
__global__ __launch_bounds__(256)
void fixup(const float* __restrict__ x, const float* __restrict__ proto,
           const int* __restrict__ n1w, const int* __restrict__ n2w,
           float* __restrict__ out) {
    int tid = threadIdx.x;
    int lane = tid & 63, wv = tid >> 6;
    long long pair = (long long)blockIdx.x * 4 + wv;
    if (pair >= (long long)BATCH * PROT) return;
    int b = (int)(pair / PROT), p = (int)(pair % PROT);
    int n1 = n1w[(size_t)b * PPAD + p];
    int n2 = n2w[(size_t)b * PPAD + p];
    int d0 = lane, d1 = lane + 64;
    const float* xb = x + (size_t)b * DDIM * NPTS;
    float xA0 = xb[(size_t)d0 * NPTS + n1], xA1 = xb[(size_t)d1 * NPTS + n1];
    float xB0 = xb[(size_t)d0 * NPTS + n2], xB1 = xb[(size_t)d1 * NPTS + n2];
    float pa0 = proto[(size_t)p * DDIM + d0], pa1 = proto[(size_t)p * DDIM + d1];
    float sxpA = xA0 * pa0 + xA1 * pa1;
    float sxpB = xB0 * pa0 + xB1 * pa1;
    float sx2A = xA0 * xA0 + xA1 * xA1;
    float sx2B = xB0 * xB0 + xB1 * xB1;
    float sp2  = pa0 * pa0 + pa1 * pa1;
    #pragma unroll
    for (int m = 1; m < 64; m <<= 1) {
        sxpA += __shfl_xor(sxpA, m, 64);
        sxpB += __shfl_xor(sxpB, m, 64);
        sx2A += __shfl_xor(sx2A, m, 64);
        sx2B += __shfl_xor(sx2B, m, 64);
        sp2  += __shfl_xor(sp2,  m, 64);
    }
    float d2A = fmaxf(sx2A + sp2 - 2.f * sxpA, 0.f);
    float d2B = fmaxf(sx2B + sp2 - 2.f * sxpB, 0.f);
    bool selB = (d2B < d2A) || (d2B == d2A && n2 < n1);
    float d2 = selB ? d2B : d2A;
    float dm = sqrtf(d2);
    float sim = logf((dm + 1.0f) / (dm + 1e-7f));
    if (lane == 0) {
        out[(size_t)b * PROT + p] = sim;
        out[(size_t)BATCH * PROT + (size_t)b * PROT + p] = dm;
    }
    float f0 = selB ? xB0 : xA0;
    float f1 = selB ? xB1 : xA1;
    float* fo = out + (size_t)2 * BATCH * PROT + ((size_t)b * PROT + p) * DDIM;
    fo[d0] = f0;
    fo[d1] = f1;
}

// ================= fallback fp32 path (round-1 kernel, known-good) =================
#define TP 64
#define TN 64
__global__ void p2_kernel(const float* __restrict__ proto, float* __restrict__ p2) {
    int p = blockIdx.x * blockDim.x + threadIdx.x;
    if (p >= PROT) return;
    const float4* pr = reinterpret_cast<const float4*>(proto + (size_t)p * DDIM);
    float s = 0.f;
    #pragma unroll
    for (int i = 0; i < DDIM / 4; ++i) {
        float4 v = pr[i];
        s += v.x * v.x + v.y * v.y + v.z * v.z + v.w * v.w;
    }
    p2[p] = s;
}
__global__ void x2_kernel(const float* __restrict__ x, float* __restrict__ x2) {
    int idx = blockIdx.x * blockDim.x + threadIdx.x;
    if (idx >= BATCH * NPTS) return;
    int b = idx / NPTS, n = idx - b * NPTS;
    const float* xp = x + (size_t)b * DDIM * NPTS + n;
    float s = 0.f;
    #pragma unroll 8
    for (int d = 0; d < DDIM; ++d) { float v = xp[(size_t)d * NPTS]; s += v * v; }
    x2[idx] = s;
}
__global__ __launch_bounds__(256, 2)
void proto_main(const float* __restrict__ x, const float* __restrict__ proto,
                const float* __restrict__ p2, const float* __restrict__ x2,
                float* __restrict__ out) {
    __shared__ __align__(16) float xs[DDIM][TN];
    __shared__ __align__(16) float pst[DDIM][TP];
    __shared__ float p2s[TP];
    __shared__ float x2s[TN];
    __shared__ float red_d2[16][TP];
    __shared__ int   red_n[16][TP];
    __shared__ int   bestn_s[TP];
    const int b = blockIdx.y;
    const int pbase = blockIdx.x * TP;
    const int tid = threadIdx.x;
    {
        #pragma unroll
        for (int it = 0; it < (TP * DDIM / 4) / 256; ++it) {
            int idx = it * 256 + tid;
            int p = idx / (DDIM / 4);
            int dq = idx - p * (DDIM / 4);
            int gp = min(pbase + p, PROT - 1);
            float4 v = reinterpret_cast<const float4*>(proto)[(size_t)gp * (DDIM / 4) + dq];
            pst[dq * 4 + 0][p] = v.x; pst[dq * 4 + 1][p] = v.y;
            pst[dq * 4 + 2][p] = v.z; pst[dq * 4 + 3][p] = v.w;
        }
        if (tid < TP) p2s[tid] = p2[min(pbase + tid, PROT - 1)];
    }
    const int tn = tid >> 4;
    const int tp = tid & 15;
    float best[4]; int bestn[4];
    #pragma unroll
    for (int j = 0; j < 4; ++j) { best[j] = 1e30f; bestn[j] = 0; }
    for (int n0 = 0; n0 < NPTS; n0 += TN) {
        __syncthreads();
        {
            int r = tid >> 4, c = tid & 15;
            #pragma unroll
            for (int it = 0; it < 8; ++it) {
                int row = it * 16 + r;
                float4 v = *reinterpret_cast<const float4*>(
                    x + ((size_t)(b * DDIM + row)) * NPTS + n0 + c * 4);
                *reinterpret_cast<float4*>(&xs[row][c * 4]) = v;
            }
        }
        if (tid < TN) x2s[tid] = x2[b * NPTS + n0 + tid];
        __syncthreads();
        float acc[4][4];
        #pragma unroll
        for (int i = 0; i < 4; ++i)
            #pragma unroll
            for (int j = 0; j < 4; ++j) acc[i][j] = 0.f;
        #pragma unroll 16
        for (int d = 0; d < DDIM; ++d) {
            const float4 a = *reinterpret_cast<const float4*>(&xs[d][tn * 4]);
            const float4 bv = *reinterpret_cast<const float4*>(&pst[d][tp * 4]);
            const float av[4] = {a.x, a.y, a.z, a.w};
            const float bw[4] = {bv.x, bv.y, bv.z, bv.w};
            #pragma unroll
            for (int i = 0; i < 4; ++i)
                #pragma unroll
                for (int j = 0; j < 4; ++j) acc[i][j] = fmaf(av[i], bw[j], acc[i][j]);
        }
        #pragma unroll
        for (int i = 0; i < 4; ++i) {
            float xv = x2s[tn * 4 + i];
            int n = n0 + tn * 4 + i;
            #pragma unroll
            for (int j = 0; j < 4; ++j) {
                float d2 = xv + p2s[tp * 4 + j] - 2.0f * acc[i][j];
                if (d2 < best[j]) { best[j] = d2; bestn[j] = n; }
            }
        }
    }
    #pragma unroll
    for (int j = 0; j < 4; ++j) {
        red_d2[tn][tp * 4 + j] = best[j];
        red_n[tn][tp * 4 + j] = bestn[j];
    }
    __syncthreads();
    if (tid < TP) {
        float bd = red_d2[0][tid]; int bn = red_n[0][tid];
        #pragma unroll
        for (int t = 1; t < 16; ++t) {
            float dv = red_d2[t][tid]; int nv = red_n[t][tid];
            if (dv < bd || (dv == bd && nv < bn)) { bd = dv; bn = nv; }
        }
        int gp = pbase + tid;
        if (gp < PROT) {
            float d2c = fmaxf(bd, 0.f);
            float dmin = sqrtf(d2c);
            float sim = logf((dmin + 1.0f) / (dmin + 1e-7f));
            out[(size_t)b * PROT + gp] = sim;
            out[(size_t)BATCH * PROT + (size_t)b * PROT + gp] = dmin;
        }
        bestn_s[tid] = bn;
    }
    __syncthreads();
    {
        int pl = tid >> 2, dbase = (tid & 3) * 32;
        int gp = pbase + pl;
        if (gp < PROT) {
            int n = bestn_s[pl];
            float* dst = out + (size_t)2 * BATCH * PROT + ((size_t)(b * PROT + gp)) * DDIM + dbase;
            const float* src = x + ((size_t)(b * DDIM + dbase)) * NPTS + n;
            #pragma unroll 8
            for (int d = 0; d < 32; ++d) dst[d] = src[(size_t)d * NPTS];
        }
    }
}

extern "C" void kernel_launch(void* const* d_in, const int* in_sizes, int n_in,
                              void* d_out, int out_size, void* d_ws, size_t ws_size,
                              hipStream_t stream) {
    const float* x = (const float*)d_in[0];       // [16,128,56,56]
    const float* proto = (const float*)d_in[1];   // [1,2000,128]
    float* out = (float*)d_out;
    float* ws = (float*)d_ws;

    if (ws_size >= WS_NEED) {
        float* x2 = ws + WS_X2;
        int* n1w = (int*)(ws + WS_N1);
        int* n2w = (int*)(ws + WS_N2);
        unsigned short* pt = (unsigned short*)(ws + WS_PT);
        unsigned short* xt = (unsigned short*)(ws + WS_XT);

        pp_p<<<PPAD / 256, 256, 0, stream>>>(proto, pt);
        pp_x<<<dim3(NPTS / 64, BATCH), 256, 0, stream>>>(x, xt, x2);
        proto_mfma<<<dim3(BATCH, PPAD / 64), 256, 0, stream>>>(xt, pt, x2, n1w, n2w);
        fixup<<<(BATCH * PROT) / 4, 256, 0, stream>>>(x, proto, n1w, n2w, out);
    } else {
        float* p2 = ws;
        float* x2 = ws + 2048;
        p2_kernel<<<(PROT + 255) / 256, 256, 0, stream>>>(proto, p2);
        x2_kernel<<<(BATCH * NPTS + 255) / 256, 256, 0, stream>>>(x, x2);
        dim3 grid((PROT + TP - 1) / TP, BATCH);
        proto_main<<<grid, 256, 0, stream>>>(x, proto, p2, x2, out);
    }
}

// Round 3
// 154.237 us; speedup vs baseline: 2.7123x; 1.4204x over previous
//
#include <hip/hip_runtime.h>
#include <hip/hip_bf16.h>
#include <cmath>

#define DDIM 128
#define NPTS 3136   // 56*56
#define NCHUNK 196  // NPTS/16
#define BATCH 16
#define PROT 2000
#define PPAD 2048   // 32 tiles * 64

typedef __attribute__((ext_vector_type(8))) short bf16x8;
typedef __attribute__((ext_vector_type(4))) float f32x4;
typedef __attribute__((ext_vector_type(4))) unsigned int u32x4;

// ---- workspace layout (float indices) ----
#define WS_X2   0                      // 50176
#define WS_N1   50176                  // 32768
#define WS_N2   82944                  // 32768
#define WS_PT   115712                 // 262144 (= 524288 shorts, 2048x256)
#define WS_XT   377856                 // 6422528 (= 16*196*8192 bytes)
#define WS_XFT  6800384                // 6422528 (16*3136*128 f32)
#define WS_MID  ((size_t)6800384 * 4)
#define WS_BIG  ((size_t)13222912 * 4)

// ---------------- bf16 split helpers ----------------
__device__ inline unsigned short bf16rn(float a) {
    unsigned u = __float_as_uint(a);
    unsigned r = u + 0x7FFFu + ((u >> 16) & 1u);
    return (unsigned short)(r >> 16);
}
__device__ inline void split2(float a, unsigned short& h, unsigned short& l) {
    h = bf16rn(a);
    float hf = __uint_as_float(((unsigned)h) << 16);
    l = bf16rn(a - hf);
}

__device__ __forceinline__ void gload_lds16(const void* g, void* l) {
    __builtin_amdgcn_global_load_lds(
        (const __attribute__((address_space(1))) void*)g,
        (__attribute__((address_space(3))) void*)l, 16, 0, 0);
}

// ---------------- prototype pre-pass: pt[p][kk][hi/lo][32] ----------------
__global__ void pp_p(const float* __restrict__ proto, unsigned short* __restrict__ pt) {
    int p = blockIdx.x * blockDim.x + threadIdx.x; // 0..2047
    if (p >= PPAD) return;
    int ps = min(p, PROT - 1);
    const float* src = proto + (size_t)ps * DDIM;
    unsigned short* dst = pt + (size_t)p * 256;
    for (int kk = 0; kk < 4; ++kk) {
        for (int j = 0; j < 32; ++j) {
            unsigned short h, l;
            split2(src[kk * 32 + j], h, l);
            dst[kk * 64 + j] = h;
            dst[kk * 64 + 32 + j] = l;
        }
    }
}

// ---------------- x pre-pass ----------------
// Emits: xt  = bf16-split A chunks, chunk-major [b][ci][8KB], XOR-swizzled
//        x2  = per-point |x|^2
//        xfT = transposed fp32 features [b][n][d] (optional)
__global__ __launch_bounds__(256)
void pp_x(const float* __restrict__ x, unsigned short* __restrict__ xt,
          float* __restrict__ x2, float* __restrict__ xfT) {
    __shared__ float xs[DDIM][64];
    int b = blockIdx.y;
    int n0 = blockIdx.x * 64;
    int tid = threadIdx.x;
    {
        int r = tid >> 4, c = tid & 15;
        #pragma unroll
        for (int it = 0; it < 8; ++it) {
            int row = it * 16 + r;
            f32x4 v = *(const f32x4*)(x + ((size_t)(b * DDIM + row)) * NPTS + n0 + c * 4);
            *(f32x4*)(&xs[row][c * 4]) = v;
        }
    }
    __syncthreads();
    if (tid < 64) {
        float s = 0.f;
        #pragma unroll 8
        for (int d = 0; d < DDIM; ++d) { float v = xs[d][tid]; s = fmaf(v, v, s); }
        x2[b * NPTS + n0 + tid] = s;
    }
    int n = tid & 63, kk = tid >> 6;
    int nl = n & 15, ci = (n0 + n) >> 4;
    unsigned int hw[16], lw[16];
    #pragma unroll
    for (int j = 0; j < 16; ++j) {
        unsigned short h0, l0, h1, l1;
        split2(xs[kk * 32 + 2 * j][n], h0, l0);
        split2(xs[kk * 32 + 2 * j + 1][n], h1, l1);
        hw[j] = (unsigned)h0 | ((unsigned)h1 << 16);
        lw[j] = (unsigned)l0 | ((unsigned)l1 << 16);
    }
    char* cb = (char*)xt + ((size_t)b * NCHUNK + ci) * 8192;
    int swz = (nl & 7) << 4;
    #pragma unroll
    for (int q = 0; q < 4; ++q) {
        int ohi = nl * 512 + kk * 128 + q * 16;
        *(u32x4*)(cb + (ohi ^ swz)) = *(u32x4*)(&hw[q * 4]);
        *(u32x4*)(cb + ((ohi + 64) ^ swz)) = *(u32x4*)(&lw[q * 4]);
    }
    if (xfT) {
        float* fo = xfT + ((size_t)b * NPTS + n0 + n) * DDIM + kk * 32;
        #pragma unroll 8
        for (int j = 0; j < 32; ++j) fo[j] = xs[kk * 32 + j][n];
    }
}

// ---------------- main MFMA kernel ----------------
// grid (32 ptile, 16 b) XCD-swizzled; block 512 = 8 waves = (2 psg x 4 nq).
// B resident in regs (2 ps/wave); A double-buffered in LDS via global_load_lds.
__global__ __launch_bounds__(512, 4)
void proto_mfma(const unsigned short* __restrict__ xt,
                const unsigned short* __restrict__ pt,
                const float* __restrict__ x2,
                int* __restrict__ n1w, int* __restrict__ n2w) {
    __shared__ char As[2][4][8192];          // 64 KB
    __shared__ float rb1[4][64], rb2[4][64]; // 2 KB
    __shared__ int   rn1[4][64], rn2[4][64]; // 2 KB

    int lid = blockIdx.x + 32 * blockIdx.y;        // 0..511
    int sid = (lid & 7) * 64 + (lid >> 3);         // bijective XCD swizzle (512 % 8 == 0)
    int b = sid >> 5;
    int pbase = (sid & 31) * 64;

    int tid = threadIdx.x;
    int lane = tid & 63, wave = tid >> 6;
    int psg = wave & 1, nq = wave >> 1;
    int l15 = lane & 15, lg = lane >> 4;

    // B fragments: 2 ps x 4 kk x {hi,lo} = 64 VGPR, resident
    bf16x8 Bh[2][4], Bl[2][4];
    #pragma unroll
    for (int ps = 0; ps < 2; ++ps) {
        int p = pbase + psg * 32 + ps * 16 + l15;
        const unsigned short* bp = pt + (size_t)p * 256 + lg * 8;
        #pragma unroll
        for (int kk = 0; kk < 4; ++kk) {
            Bh[ps][kk] = *(const bf16x8*)(bp + kk * 64);
            Bl[ps][kk] = *(const bf16x8*)(bp + kk * 64 + 32);
        }
    }

    const char* srcBase = (const char*)xt + (size_t)b * NCHUNK * 8192;
    // swizzled per-lane LDS fragment base (bits 7..8 clear -> XOR with kk/s offsets ok)
    int preA = ((l15 << 9) | (lg << 4)) ^ ((l15 & 7) << 4);

    float b1[2], b2[2];
    int   i1[2], i2[2];
    #pragma unroll
    for (int ps = 0; ps < 2; ++ps) { b1[ps] = 3e38f; b2[ps] = 3e38f; i1[ps] = 0; i2[ps] = 0; }

    // prologue: stage first chunk of this wave's stream
    {
        const char* src = srcBase + (size_t)nq * 8192 + (size_t)lane * 16;
        #pragma unroll
        for (int i = 0; i < 8; ++i)
            gload_lds16(src + i * 1024, &As[0][nq][i * 1024]);
    }
    __syncthreads();

    #pragma unroll 1
    for (int t = 0; t < 49; ++t) {
        int cur = t & 1;
        int c = nq + 4 * t;
        if (t < 48) {
            const char* src = srcBase + ((size_t)c + 4) * 8192 + (size_t)lane * 16;
            #pragma unroll
            for (int i = 0; i < 8; ++i)
                gload_lds16(src + i * 1024, &As[cur ^ 1][nq][i * 1024]);
        }
        const char* ab = &As[cur][nq][0];
        float x2r[4];
        {
            const float* xp = x2 + b * NPTS + c * 16 + lg * 4;
            #pragma unroll
            for (int rr = 0; rr < 4; ++rr) x2r[rr] = xp[rr];
        }

        f32x4 acc[2];
        acc[0] = {0.f, 0.f, 0.f, 0.f};
        acc[1] = {0.f, 0.f, 0.f, 0.f};
        #pragma unroll
        for (int kk = 0; kk < 4; ++kk) {
            bf16x8 Ah = *(const bf16x8*)(ab + (preA ^ (kk * 128)));
            bf16x8 Al = *(const bf16x8*)(ab + (preA ^ (kk * 128 + 64)));
            acc[0] = __builtin_amdgcn_mfma_f32_16x16x32_bf16(Ah, Bh[0][kk], acc[0], 0, 0, 0);
            acc[1] = __builtin_amdgcn_mfma_f32_16x16x32_bf16(Ah, Bh[1][kk], acc[1], 0, 0, 0);
            acc[0] = __builtin_amdgcn_mfma_f32_16x16x32_bf16(Ah, Bl[0][kk], acc[0], 0, 0, 0);
            acc[1] = __builtin_amdgcn_mfma_f32_16x16x32_bf16(Ah, Bl[1][kk], acc[1], 0, 0, 0);
            acc[0] = __builtin_amdgcn_mfma_f32_16x16x32_bf16(Al, Bh[0][kk], acc[0], 0, 0, 0);
            acc[1] = __builtin_amdgcn_mfma_f32_16x16x32_bf16(Al, Bh[1][kk], acc[1], 0, 0, 0);
        }

        int nb = c * 16 + lg * 4;
        #pragma unroll
        for (int ps = 0; ps < 2; ++ps) {
            #pragma unroll
            for (int rr = 0; rr < 4; ++rr) {
                float v = fmaf(acc[ps][rr], -2.f, x2r[rr]);   // = d2 - p2[p]
                int n = nb + rr;
                bool c1 = v < b1[ps];
                bool c2 = v < b2[ps];
                i2[ps] = c1 ? i1[ps] : (c2 ? n : i2[ps]);
                b2[ps] = c1 ? b1[ps] : (c2 ? v : b2[ps]);
                i1[ps] = c1 ? n : i1[ps];
                b1[ps] = c1 ? v : b1[ps];
            }
        }
        __syncthreads();
    }

    // ---- reduce across the 4 row-groups (lanes l, l+16, l+32, l+48) ----
    #pragma unroll
    for (int m = 16; m <= 32; m <<= 1) {
        #pragma unroll
        for (int ps = 0; ps < 2; ++ps) {
            float c1v = __shfl_xor(b1[ps], m, 64);
            float c2v = __shfl_xor(b2[ps], m, 64);
            int   cn1 = __shfl_xor(i1[ps], m, 64);
            int   cn2 = __shfl_xor(i2[ps], m, 64);
            bool cl = (c1v < b1[ps]) || (c1v == b1[ps] && cn1 < i1[ps]);
            float m1 = cl ? c1v : b1[ps]; int mn1 = cl ? cn1 : i1[ps];
            float w1 = cl ? b1[ps] : c1v; int wn1 = cl ? i1[ps] : cn1;
            bool tt = (b2[ps] < c2v) || (b2[ps] == c2v && i2[ps] < cn2);
            float s2 = tt ? b2[ps] : c2v; int sn2 = tt ? i2[ps] : cn2;
            bool u = (w1 < s2) || (w1 == s2 && wn1 < sn2);
            b1[ps] = m1; i1[ps] = mn1;
            b2[ps] = u ? w1 : s2; i2[ps] = u ? wn1 : sn2;
        }
    }

    if (lg == 0) {
        #pragma unroll
        for (int ps = 0; ps < 2; ++ps) {
            int idx = psg * 32 + ps * 16 + l15;
            rb1[nq][idx] = b1[ps]; rb2[nq][idx] = b2[ps];
            rn1[nq][idx] = i1[ps]; rn2[nq][idx] = i2[ps];
        }
    }
    __syncthreads();
    if (tid < 64) {
        float B1 = rb1[0][tid], B2 = rb2[0][tid];
        int   N1 = rn1[0][tid], N2 = rn2[0][tid];
        #pragma unroll
        for (int w = 1; w < 4; ++w) {
            float c1v = rb1[w][tid], c2v = rb2[w][tid];
            int   cn1 = rn1[w][tid], cn2 = rn2[w][tid];
            bool cl = (c1v < B1) || (c1v == B1 && cn1 < N1);
            float m1 = cl ? c1v : B1; int mn1 = cl ? cn1 : N1;
            float w1 = cl ? B1 : c1v; int wn1 = cl ? N1 : cn1;
            bool tt = (B2 < c2v) || (B2 == c2v && N2 < cn2);
            float s2 = tt ? B2 : c2v; int sn2 = tt ? N2 : cn2;
            bool u = (w1 < s2) || (w1 == s2 && wn1 < sn2);
            B1 = m1; N1 = mn1;
            B2 = u ? w1 : s2; N2 = u ? wn1 : sn2;
        }
        n1w[(size_t)b * PPAD + pbase + tid] = N1;
        n2w[(size_t)b * PPAD + pbase + tid] = N2;
    }
}

// ---------------- exact fp32 fixup + all output writes ----------------
// MODE 0: coalesced via xfT; MODE 1: strided from x.
template<int MODE>
__global__ __launch_bounds__(256)
void fixup(const float* __restrict__ x, const float* __restrict__ xfT,
           const float* __restrict__ proto,
           const int* __restrict__ n1w, const int* __restrict__ n2w,
           float* __restrict__ out) {
    int tid = threadIdx.x;
    int lane = tid & 63, wv = tid >> 6;
    long long pair = (long long)blockIdx.x * 4 + wv;
    if (pair >= (long long)BATCH * PROT) return;
    int b = (int)(pair / PROT), p = (int)(pair % PROT);
    int n1 = n1w[(size_t)b * PPAD + p];
    int n2 = n2w[(size_t)b * PPAD + p];
    int d0 = lane, d1 = lane + 64;
    float xA0, xA1, xB0, xB1;
    if (MODE == 0) {
        const float* fA = xfT + ((size_t)b * NPTS + n1) * DDIM;
        const float* fB = xfT + ((size_t)b * NPTS + n2) * DDIM;
        xA0 = fA[d0]; xA1 = fA[d1];
        xB0 = fB[d0]; xB1 = fB[d1];
    } else {
        const float* xb = x + (size_t)b * DDIM * NPTS;
        xA0 = xb[(size_t)d0 * NPTS + n1]; xA1 = xb[(size_t)d1 * NPTS + n1];
        xB0 = xb[(size_t)d0 * NPTS + n2]; xB1 = xb[(size_t)d1 * NPTS + n2];
    }
    float pa0 = proto[(size_t)p * DDIM + d0], pa1 = proto[(size_t)p * DDIM + d1];
    float sxpA = xA0 * pa0 + xA1 * pa1;
    float sxpB = xB0 * pa0 + xB1 * pa1;
    float sx2A = xA0 * xA0 + xA1 * xA1;
    float sx2B = xB0 * xB0 + xB1 * xB1;
    float sp2  = pa0 * pa0 + pa1 * pa1;
    #pragma unroll
    for (int m = 1; m < 64; m <<= 1) {
        sxpA += __shfl_xor(sxpA, m, 64);
        sxpB += __shfl_xor(sxpB, m, 64);
        sx2A += __shfl_xor(sx2A, m, 64);
        sx2B += __shfl_xor(sx2B, m, 64);
        sp2  += __shfl_xor(sp2,  m, 64);
    }
    float d2A = fmaxf(sx2A + sp2 - 2.f * sxpA, 0.f);
    float d2B = fmaxf(sx2B + sp2 - 2.f * sxpB, 0.f);
    bool selB = (d2B < d2A) || (d2B == d2A && n2 < n1);
    float d2 = selB ? d2B : d2A;
    float dm = sqrtf(d2);
    float sim = logf((dm + 1.0f) / (dm + 1e-7f));
    if (lane == 0) {
        out[(size_t)b * PROT + p] = sim;
        out[(size_t)BATCH * PROT + (size_t)b * PROT + p] = dm;
    }
    float f0 = selB ? xB0 : xA0;
    float f1 = selB ? xB1 : xA1;
    float* fo = out + (size_t)2 * BATCH * PROT + ((size_t)b * PROT + p) * DDIM;
    fo[d0] = f0;
    fo[d1] = f1;
}

// ================= fallback fp32 path (round-1, known-good; dead in practice) ====
#define TP 64
#define TN 64
__global__ void p2_kernel(const float* __restrict__ proto, float* __restrict__ p2) {
    int p = blockIdx.x * blockDim.x + threadIdx.x;
    if (p >= PROT) return;
    const float4* pr = reinterpret_cast<const float4*>(proto + (size_t)p * DDIM);
    float s = 0.f;
    #pragma unroll
    for (int i = 0; i < DDIM / 4; ++i) {
        float4 v = pr[i];
        s += v.x * v.x + v.y * v.y + v.z * v.z + v.w * v.w;
    }
    p2[p] = s;
}
__global__ void x2_kernel(const float* __restrict__ x, float* __restrict__ x2) {
    int idx = blockIdx.x * blockDim.x + threadIdx.x;
    if (idx >= BATCH * NPTS) return;
    int b = idx / NPTS, n = idx - b * NPTS;
    const float* xp = x + (size_t)b * DDIM * NPTS + n;
    float s = 0.f;
    #pragma unroll 8
    for (int d = 0; d < DDIM; ++d) { float v = xp[(size_t)d * NPTS]; s += v * v; }
    x2[idx] = s;
}
__global__ __launch_bounds__(256, 2)
void proto_main(const float* __restrict__ x, const float* __restrict__ proto,
                const float* __restrict__ p2, const float* __restrict__ x2,
                float* __restrict__ out) {
    __shared__ __align__(16) float xs[DDIM][TN];
    __shared__ __align__(16) float pst[DDIM][TP];
    __shared__ float p2s[TP];
    __shared__ float x2s[TN];
    __shared__ float red_d2[16][TP];
    __shared__ int   red_n[16][TP];
    __shared__ int   bestn_s[TP];
    const int b = blockIdx.y;
    const int pbase = blockIdx.x * TP;
    const int tid = threadIdx.x;
    {
        #pragma unroll
        for (int it = 0; it < (TP * DDIM / 4) / 256; ++it) {
            int idx = it * 256 + tid;
            int p = idx / (DDIM / 4);
            int dq = idx - p * (DDIM / 4);
            int gp = min(pbase + p, PROT - 1);
            float4 v = reinterpret_cast<const float4*>(proto)[(size_t)gp * (DDIM / 4) + dq];
            pst[dq * 4 + 0][p] = v.x; pst[dq * 4 + 1][p] = v.y;
            pst[dq * 4 + 2][p] = v.z; pst[dq * 4 + 3][p] = v.w;
        }
        if (tid < TP) p2s[tid] = p2[min(pbase + tid, PROT - 1)];
    }
    const int tn = tid >> 4;
    const int tp = tid & 15;
    float best[4]; int bestn[4];
    #pragma unroll
    for (int j = 0; j < 4; ++j) { best[j] = 1e30f; bestn[j] = 0; }
    for (int n0 = 0; n0 < NPTS; n0 += TN) {
        __syncthreads();
        {
            int r = tid >> 4, c = tid & 15;
            #pragma unroll
            for (int it = 0; it < 8; ++it) {
                int row = it * 16 + r;
                float4 v = *reinterpret_cast<const float4*>(
                    x + ((size_t)(b * DDIM + row)) * NPTS + n0 + c * 4);
                *reinterpret_cast<float4*>(&xs[row][c * 4]) = v;
            }
        }
        if (tid < TN) x2s[tid] = x2[b * NPTS + n0 + tid];
        __syncthreads();
        float acc[4][4];
        #pragma unroll
        for (int i = 0; i < 4; ++i)
            #pragma unroll
            for (int j = 0; j < 4; ++j) acc[i][j] = 0.f;
        #pragma unroll 16
        for (int d = 0; d < DDIM; ++d) {
            const float4 a = *reinterpret_cast<const float4*>(&xs[d][tn * 4]);
            const float4 bv = *reinterpret_cast<const float4*>(&pst[d][tp * 4]);
            const float av[4] = {a.x, a.y, a.z, a.w};
            const float bw[4] = {bv.x, bv.y, bv.z, bv.w};
            #pragma unroll
            for (int i = 0; i < 4; ++i)
                #pragma unroll
                for (int j = 0; j < 4; ++j) acc[i][j] = fmaf(av[i], bw[j], acc[i][j]);
        }
        #pragma unroll
        for (int i = 0; i < 4; ++i) {
            float xv = x2s[tn * 4 + i];
            int n = n0 + tn * 4 + i;
            #pragma unroll
            for (int j = 0; j < 4; ++j) {
                float d2 = xv + p2s[tp * 4 + j] - 2.0f * acc[i][j];
                if (d2 < best[j]) { best[j] = d2; bestn[j] = n; }
            }
        }
    }
    #pragma unroll
    for (int j = 0; j < 4; ++j) {
        red_d2[tn][tp * 4 + j] = best[j];
        red_n[tn][tp * 4 + j] = bestn[j];
    }
    __syncthreads();
    if (tid < TP) {
        float bd = red_d2[0][tid]; int bn = red_n[0][tid];
        #pragma unroll
        for (int t = 1; t < 16; ++t) {
            float dv = red_d2[t][tid]; int nv = red_n[t][tid];
            if (dv < bd || (dv == bd && nv < bn)) { bd = dv; bn = nv; }
        }
        int gp = pbase + tid;
        if (gp < PROT) {
            float d2c = fmaxf(bd, 0.f);
            float dmin = sqrtf(d2c);
            float sim = logf((dmin + 1.0f) / (dmin + 1e-7f));
            out[(size_t)b * PROT + gp] = sim;
            out[(size_t)BATCH * PROT + (size_t)b * PROT + gp] = dmin;
        }
        bestn_s[tid] = bn;
    }
    __syncthreads();
    {
        int pl = tid >> 2, dbase = (tid & 3) * 32;
        int gp = pbase + pl;
        if (gp < PROT) {
            int n = bestn_s[pl];
            float* dst = out + (size_t)2 * BATCH * PROT + ((size_t)(b * PROT + gp)) * DDIM + dbase;
            const float* src = x + ((size_t)(b * DDIM + dbase)) * NPTS + n;
            #pragma unroll 8
            for (int d = 0; d < 32; ++d) dst[d] = src[(size_t)d * NPTS];
        }
    }
}

extern "C" void kernel_launch(void* const* d_in, const int* in_sizes, int n_in,
                              void* d_out, int out_size, void* d_ws, size_t ws_size,
                              hipStream_t stream) {
    const float* x = (const float*)d_in[0];       // [16,128,56,56]
    const float* proto = (const float*)d_in[1];   // [1,2000,128]
    float* out = (float*)d_out;
    float* ws = (float*)d_ws;

    if (ws_size >= WS_MID) {
        bool big = (ws_size >= WS_BIG);
        float* x2 = ws + WS_X2;
        int* n1w = (int*)(ws + WS_N1);
        int* n2w = (int*)(ws + WS_N2);
        unsigned short* pt = (unsigned short*)(ws + WS_PT);
        unsigned short* xt = (unsigned short*)(ws + WS_XT);
        float* xfT = big ? (ws + WS_XFT) : nullptr;

        pp_p<<<PPAD / 256, 256, 0, stream>>>(proto, pt);
        pp_x<<<dim3(NPTS / 64, BATCH), 256, 0, stream>>>(x, xt, x2, xfT);
        proto_mfma<<<dim3(32, BATCH), 512, 0, stream>>>(xt, pt, x2, n1w, n2w);
        if (big)
            fixup<0><<<(BATCH * PROT) / 4, 256, 0, stream>>>(x, xfT, proto, n1w, n2w, out);
        else
            fixup<1><<<(BATCH * PROT) / 4, 256, 0, stream>>>(x, nullptr, proto, n1w, n2w, out);
    } else {
        float* p2 = ws;
        float* x2 = ws + 2048;
        p2_kernel<<<(PROT + 255) / 256, 256, 0, stream>>>(proto, p2);
        x2_kernel<<<(BATCH * NPTS + 255) / 256, 256, 0, stream>>>(x, x2);
        dim3 grid((PROT + TP - 1) / TP, BATCH);
        proto_main<<<grid, 256, 0, stream>>>(x, proto, p2, x2, out);
    }
}